// Round 6
// baseline (383.793 us; speedup 1.0000x reference)
//
#include <hip/hip_runtime.h>

// ---------------------------------------------------------------------------
// Convnet: 8 overlapping sections, conv [32x16] x 128 ch, threshold 15, pool
// (400,16), winner-take-all -> single channel index.
//
// R5: conv reverted to R2's proven 85us structure (M=256 block, Mw=2/Nw=4 per
//     wave, 2 blocks/CU — best ratio under the 256-reg/wave occupancy cliff).
//     Winner folded into conv via completion counter (last block computes it
//     register-resident) — kills the 3rd launch. 3072-block persistent grid
//     (blocks 0..47 do 2 tiles) removes the 6.09-cohort ragged tail.
// ---------------------------------------------------------------------------

using short8 = __attribute__((ext_vector_type(8))) short;
using f32x16 = __attribute__((ext_vector_type(16))) float;

__device__ __forceinline__ unsigned short f2bf(float f) {
  unsigned u = __float_as_uint(f);
  u += 0x7FFFu + ((u >> 16) & 1u);   // RNE
  return (unsigned short)(u >> 16);
}

#define THRESH 15.0f
#define N_TILES 3072
#define TOT_TILES 3120

// ---------------- prep: Wp[((s*64+p)*128 + c)*8 + e] = bf16(W[s][c][k=p*8+e])
__global__ __launch_bounds__(256) void prep_kernel(const float* __restrict__ W,
                                                   unsigned short* __restrict__ Wp,
                                                   int* __restrict__ pool,
                                                   unsigned* __restrict__ cnt) {
  int t = blockIdx.x * 256 + threadIdx.x;   // 65536 threads
  if (t < 15360) pool[t] = 0;
  if (t == 65535) *cnt = 0;
  int s = t >> 13;
  int r = t & 8191;
  int c = r >> 6;
  int p = r & 63;
  const float* src = W + ((s * 128 + c) * 512 + p * 8);
  float4 v0 = *(const float4*)(src);
  float4 v1 = *(const float4*)(src + 4);
  short8 o;
  o[0] = (short)f2bf(v0.x); o[1] = (short)f2bf(v0.y);
  o[2] = (short)f2bf(v0.z); o[3] = (short)f2bf(v0.w);
  o[4] = (short)f2bf(v1.x); o[5] = (short)f2bf(v1.y);
  o[6] = (short)f2bf(v1.z); o[7] = (short)f2bf(v1.w);
  *(short8*)(Wp + ((s * 64 + p) * 128 + c) * 8) = o;
}

// ---------------- conv + threshold + pool-OR + (last block) winner
// tiles: 8 s * 13 t-tiles(32) * 30 fo-tiles(8) = 3120, on 3072 blocks
// block: M = 256 (32 t x 8 fo), N = 128 ch, K = 512 (k = kt*16+kf)
// wave w: fo offsets {2w, 2w+1}; 32x32x16 MFMA:
//   A[m=lane&31][k=(lane>>5)*8+j], B[k][n=lane&31], D col=lane&31
__global__ __launch_bounds__(256, 2) void conv_pool_kernel(const float* __restrict__ X,
                                                           const unsigned short* __restrict__ Wp,
                                                           int* __restrict__ pool,
                                                           unsigned* __restrict__ cnt,
                                                           float* __restrict__ out) {
  __shared__ __align__(16) unsigned short Ash[8 * 1512];    // 24192 B
  __shared__ __align__(16) unsigned short Bsh[2 * 8192];    // 32768 B (dbuf)
  __shared__ unsigned poolbits[32];
  __shared__ int sh_done, sh_v, sh_best;

  const int tid = threadIdx.x;
  const int w = tid >> 6, l = tid & 63;
  const int m31 = l & 31, ko = l >> 5;

  // per-lane LDS bases (tile-independent)
  const unsigned short* abase = &Ash[(2 * w) * 1512 + m31 * 24 + ko * 8];
  const int boff = ko * 1024 + m31 * 8;

  for (int tile = blockIdx.x; tile < TOT_TILES; tile += N_TILES) {
    const int s   = tile / 390;
    const int rem = tile % 390;
    const int tt  = rem / 30;
    const int ft  = rem % 30;
    const int t0  = (tt == 12) ? 368 : tt * 32;   // overlap recompute, OR idempotent
    const int fo0 = ft * 8, fp = ft >> 1;
    const int srow = s * 400 + t0;                // max 3168; +62 = 3230 in-bounds

    if (tid < 32) poolbits[tid] = 0;

    // ---- stage A copies: 8 d x 63 r x 2 halves = 1008 b128 writes
    for (int i = tid; i < 1008; i += 256) {
      int d = i / 126, rj = i % 126;
      int r = rj >> 1, h = rj & 1;
      const float* xs = X + (srow + r) * 256 + fo0 + d + h * 8;
      short8 o;
#pragma unroll
      for (int e = 0; e < 8; ++e) o[e] = (short)f2bf(xs[e]);
      *(short8*)&Ash[d * 1512 + r * 24 + h * 8] = o;
    }

    f32x16 acc[2][4];
#pragma unroll
    for (int a = 0; a < 2; ++a)
#pragma unroll
      for (int b = 0; b < 4; ++b)
#pragma unroll
        for (int e = 0; e < 16; ++e) acc[a][b][e] = 0.f;

    const unsigned short* wbase = Wp + s * 65536;   // 64 packs * 128 ch * 8

    // issue B chunk 0 into buf 0 (drained by the next barrier)
#pragma unroll
    for (int it = 0; it < 4; ++it) {
      int off = (it * 256 + tid) * 8;
      __builtin_amdgcn_global_load_lds(
          (const __attribute__((address_space(1))) void*)(wbase + off),
          (__attribute__((address_space(3))) void*)(&Bsh[off]), 16, 0, 0);
    }
    __syncthreads();   // A copies + chunk 0 + poolbits ready

    for (int ch = 0; ch < 8; ++ch) {              // K chunks of 64 (4 kt each)
      const unsigned short* cur = Bsh + (ch & 1) * 8192;
      if (ch < 7) {                               // prefetch next chunk
        const unsigned short* gsrc = wbase + (ch + 1) * 8192;
        unsigned short* dst = Bsh + ((ch + 1) & 1) * 8192;
#pragma unroll
        for (int it = 0; it < 4; ++it) {
          int off = (it * 256 + tid) * 8;
          __builtin_amdgcn_global_load_lds(
              (const __attribute__((address_space(1))) void*)(gsrc + off),
              (__attribute__((address_space(3))) void*)(dst + off), 16, 0, 0);
        }
      }

      const unsigned short* ab = abase + ch * 96;   // row += 4 kt per chunk
      const unsigned short* bb = cur + boff;
#pragma unroll
      for (int ktr = 0; ktr < 4; ++ktr) {
        short8 a0 = *(const short8*)(ab);             // fo +0
        short8 a1 = *(const short8*)(ab + 1512);      // fo +1
        ab += 24;
#pragma unroll
        for (int nt = 0; nt < 4; ++nt) {
          short8 bfr = *(const short8*)(bb + ktr * 2048 + nt * 256);  // ch nt*32+m31
          acc[0][nt] = __builtin_amdgcn_mfma_f32_32x32x16_bf16(a0, bfr, acc[0][nt], 0, 0, 0);
          acc[1][nt] = __builtin_amdgcn_mfma_f32_32x32x16_bf16(a1, bfr, acc[1][nt], 0, 0, 0);
        }
      }
      __syncthreads();   // drains prefetch (issued ~32 MFMAs ago), frees cur
    }

    // ---- threshold + OR. Lane covers channels c = nt*32 + m31.
    unsigned sp = 0;
#pragma unroll
    for (int nt = 0; nt < 4; ++nt) {
      float m0 = -1e30f, m1 = -1e30f;
#pragma unroll
      for (int e = 0; e < 16; ++e) {
        m0 = fmaxf(m0, acc[0][nt][e]);
        m1 = fmaxf(m1, acc[1][nt][e]);
      }
      if (fmaxf(m0, m1) >= THRESH) sp |= (1u << nt);
    }
    sp |= __shfl_xor(sp, 32, 64);   // merge the two row-halves
    if (l < 32 && sp) atomicOr(&poolbits[m31], sp);
    __syncthreads();

    if (tid < 128) {
      unsigned bits = poolbits[tid & 31];
      if ((bits >> (tid >> 5)) & 1)
        __hip_atomic_store(&pool[(s * 128 + tid) * 15 + fp], 1,
                           __ATOMIC_RELAXED, __HIP_MEMORY_SCOPE_AGENT);
    }
    __syncthreads();   // protect poolbits before next tile's zeroing
  }

  // ---- completion: last block runs the winner (reference get_k_winners)
  __threadfence();
  __syncthreads();
  if (tid == 0) {
    unsigned old = __hip_atomic_fetch_add(cnt, 1u, __ATOMIC_ACQ_REL,
                                          __HIP_MEMORY_SCOPE_AGENT);
    sh_done = (old == (unsigned)(N_TILES - 1));
    sh_v = 0; sh_best = 0;
  }
  __syncthreads();
  if (!sh_done) return;
  __threadfence();

  unsigned bitsArr[8];
  int localv = 0;
#pragma unroll
  for (int it = 0; it < 8; ++it) {
    int p = tid + it * 256;
    unsigned bits = 0;
    if (p < 1920) {
      for (int s = 0; s < 8; ++s) {
        int v = __hip_atomic_load(&pool[s * 1920 + p],
                                  __ATOMIC_RELAXED, __HIP_MEMORY_SCOPE_AGENT);
        bits |= ((unsigned)v) << s;
      }
      if (bits) {
        int c = __popc(bits);
        int early = 8 - c; if (early > 7) early = 7;
        localv |= (bits >> early) & 1;
      }
    }
    bitsArr[it] = bits;
  }
  if (localv) atomicOr(&sh_v, 1);
  __syncthreads();

  const int v = sh_v * 8;   // trunc.max() * T
  int best = 0;
#pragma unroll
  for (int it = 0; it < 8; ++it) {
    int p = tid + it * 256;
    if (p < 1920) {
      unsigned bits = bitsArr[it];
      int c = __popc(bits);
      int early = 8 - c; if (early > 7) early = 7;
      int val = (bits >> early) & 1;
      int total = c * (val + v);
      int pack = (total << 12) | (4095 - p);   // max total, then smallest flat idx
      if (pack > best) best = pack;
    }
  }
  atomicMax(&sh_best, best);
  __syncthreads();

  if (tid == 0) {
    int total = sh_best >> 12;
    int p = 4095 - (sh_best & 4095);
    int feat = p / 15;
    out[0] = (total != 0) ? (float)feat : -1.0f;
  }
}

// ---------------------------------------------------------------------------
extern "C" void kernel_launch(void* const* d_in, const int* in_sizes, int n_in,
                              void* d_out, int out_size, void* d_ws, size_t ws_size,
                              hipStream_t stream) {
  (void)in_sizes; (void)n_in; (void)out_size; (void)ws_size;
  const float* X = (const float*)d_in[0];
  const float* W = (const float*)d_in[1];
  unsigned short* Wp = (unsigned short*)d_ws;              // 1,048,576 B
  int* pool = (int*)((char*)d_ws + (1 << 20));             // 61,440 B
  unsigned* cnt = (unsigned*)((char*)d_ws + (1 << 20) + 61440);

  prep_kernel<<<256, 256, 0, stream>>>(W, Wp, pool, cnt);
  conv_pool_kernel<<<N_TILES, 256, 0, stream>>>(X, Wp, pool, cnt, (float*)d_out);
}

// Round 7
// 112.337 us; speedup vs baseline: 3.4164x; 3.4164x over previous
//
#include <hip/hip_runtime.h>

// ---------------------------------------------------------------------------
// Convnet: 8 overlapping sections, conv [32x16] x 128 ch, threshold 15, pool
// (400,16), winner-take-all -> single channel index.
//
// R6: R2's proven conv skeleton (M=256 block, Mw=2/Nw=4, 2 blocks/CU, B dbuf)
//     ported to MX-scaled FP8 (mfma_scale 32x32x64_f8f6f4, scales=1.0):
//     2x FLOP/cycle and half the fragment bytes -> both limiting pipes halve.
//     Winner back to its own tiny kernel (R5 showed tail code in the hot
//     kernel wrecks register allocation). 3 kernels.
// ---------------------------------------------------------------------------

using int4v  = __attribute__((ext_vector_type(4))) int;
using int8v  = __attribute__((ext_vector_type(8))) int;
using f32x16 = __attribute__((ext_vector_type(16))) float;

#define THRESH 15.0f
#define SCALE1 0x7F7F7F7F   // E8M0 127 = 2^0 in every byte

// ---------------- prep: W fp32 -> fp8 e4m3, packed so each lane-slot row of
// 32 taps (one k32 block) is 32 contiguous bytes:
//   Wp8[((s*16 + b)*128 + c)*32 + j] = fp8(W[s][c][k=b*32+j])
__global__ __launch_bounds__(256) void prep_kernel(const float* __restrict__ W,
                                                   unsigned char* __restrict__ Wp8,
                                                   int* __restrict__ pool) {
  int t = blockIdx.x * 256 + threadIdx.x;   // 64 blocks -> 16384 threads
  if (t < 15360) pool[t] = 0;
  int s = t >> 11, r = t & 2047, c = r >> 4, b = r & 15;
  const float* src = W + ((s * 128 + c) * 512 + b * 32);
  int8v o;
#pragma unroll
  for (int i = 0; i < 8; ++i) {
    float4 v = *(const float4*)(src + i * 4);
    int p = 0;
    p = __builtin_amdgcn_cvt_pk_fp8_f32(v.x, v.y, p, false);  // bytes 0,1
    p = __builtin_amdgcn_cvt_pk_fp8_f32(v.z, v.w, p, true);   // bytes 2,3
    o[i] = p;
  }
  *(int8v*)(Wp8 + ((s * 16 + b) * 128 + c) * 32) = o;
}

// ---------------- conv + threshold + pool-OR
// grid: 8 s * 13 t-tiles(32) * 30 fo-tiles(8) = 3120 blocks, 256 threads
// block: M = 256 (32 t x 8 fo), N = 128 ch, K = 512 (k = kt*16+kf)
// wave w: fo offsets {2w, 2w+1}; mfma_scale_f32_32x32x64_f8f6f4:
//   lane holds A[m=lane&31][k=(lane>>5)*32+j] (32 B), B[k][n=lane&31] (32 B),
//   D col = lane&31 (shape-determined C/D layout). Slot j packed identically
//   on A and B sides -> any internal slot->k permutation cancels.
__global__ __launch_bounds__(256, 2) void conv_pool_kernel(const float* __restrict__ X,
                                                           const unsigned char* __restrict__ Wp8,
                                                           int* __restrict__ pool) {
  // 8 fo-shifted copies of the 63-row X patch, fp8: 16 B/row padded to 48 B
  __shared__ __align__(16) unsigned char Ash[8 * 3024];   // 24192 B
  __shared__ __align__(16) unsigned char Bsh[2 * 8192];   // 16384 B (dbuf)
  __shared__ unsigned poolbits[32];

  const int tid = threadIdx.x;
  const int bid = blockIdx.x;
  const int s   = bid / 390;
  const int rem = bid % 390;
  const int tt  = rem / 30;
  const int ft  = rem % 30;
  const int t0  = (tt == 12) ? 368 : tt * 32;   // overlap recompute; OR idempotent
  const int fo0 = ft * 8, fp = ft >> 1;
  const int srow = s * 400 + t0;                // max 3168; +62 = 3230 in-bounds

  if (tid < 32) poolbits[tid] = 0;

  // ---- stage A: 8 d x 63 r rows, 16 fp8 each (16 scalar loads + 8 cvt_pk)
  for (int i = tid; i < 504; i += 256) {
    int d = i / 63, r = i % 63;
    const float* xs = X + (srow + r) * 256 + fo0 + d;
    int4v pk;
#pragma unroll
    for (int h = 0; h < 4; ++h) {
      int q = 0;
      q = __builtin_amdgcn_cvt_pk_fp8_f32(xs[h * 4 + 0], xs[h * 4 + 1], q, false);
      q = __builtin_amdgcn_cvt_pk_fp8_f32(xs[h * 4 + 2], xs[h * 4 + 3], q, true);
      pk[h] = q;
    }
    *(int4v*)&Ash[d * 3024 + r * 48] = pk;
  }

  f32x16 acc[2][4];
#pragma unroll
  for (int a = 0; a < 2; ++a)
#pragma unroll
    for (int b = 0; b < 4; ++b)
#pragma unroll
      for (int e = 0; e < 16; ++e) acc[a][b][e] = 0.f;

  const int w = tid >> 6, l = tid & 63;
  const int m31 = l & 31, ko = l >> 5;

  const unsigned char* wbase = Wp8 + s * 65536;   // 16 k32-blocks * 128 ch * 32 B

  // per-lane LDS bases (bytes)
  const int arow = m31 * 48 + ko * 96;            // + ch*192 + rr*48
  const int aoff0 = (2 * w) * 3024 + arow;
  const int aoff1 = (2 * w + 1) * 3024 + arow;
  const int boff  = ko * 4096 + m31 * 32;         // + nt*1024 within chunk buf

  // issue B chunk 0 into buf 0 (drained by the next barrier)
#pragma unroll
  for (int it = 0; it < 2; ++it) {
    int off = (it * 256 + tid) * 16;
    __builtin_amdgcn_global_load_lds(
        (const __attribute__((address_space(1))) void*)(wbase + off),
        (__attribute__((address_space(3))) void*)(&Bsh[off]), 16, 0, 0);
  }
  __syncthreads();   // A copies + chunk 0 + poolbits ready

  for (int ch = 0; ch < 8; ++ch) {              // K chunks of 64 (4 kt each)
    const unsigned char* cur = Bsh + (ch & 1) * 8192;
    if (ch < 7) {                               // prefetch next chunk
      const unsigned char* gsrc = wbase + (ch + 1) * 8192;
      unsigned char* dst = Bsh + ((ch + 1) & 1) * 8192;
#pragma unroll
      for (int it = 0; it < 2; ++it) {
        int off = (it * 256 + tid) * 16;
        __builtin_amdgcn_global_load_lds(
            (const __attribute__((address_space(1))) void*)(gsrc + off),
            (__attribute__((address_space(3))) void*)(dst + off), 16, 0, 0);
      }
    }

    // A frags: rows kt = ch*4 + ko*2 + {0,1}, 16 B each
    int4v a0lo = *(const int4v*)&Ash[aoff0 + ch * 192];
    int4v a0hi = *(const int4v*)&Ash[aoff0 + ch * 192 + 48];
    int4v a1lo = *(const int4v*)&Ash[aoff1 + ch * 192];
    int4v a1hi = *(const int4v*)&Ash[aoff1 + ch * 192 + 48];
    int8v A0 = {a0lo[0], a0lo[1], a0lo[2], a0lo[3], a0hi[0], a0hi[1], a0hi[2], a0hi[3]};
    int8v A1 = {a1lo[0], a1lo[1], a1lo[2], a1lo[3], a1hi[0], a1hi[1], a1hi[2], a1hi[3]};

    const unsigned char* bb = cur + boff;
#pragma unroll
    for (int nt = 0; nt < 4; ++nt) {
      int4v blo = *(const int4v*)(bb + nt * 1024);
      int4v bhi = *(const int4v*)(bb + nt * 1024 + 16);
      int8v Bf = {blo[0], blo[1], blo[2], blo[3], bhi[0], bhi[1], bhi[2], bhi[3]};
      acc[0][nt] = __builtin_amdgcn_mfma_scale_f32_32x32x64_f8f6f4(
          A0, Bf, acc[0][nt], 0, 0, 0, SCALE1, 0, SCALE1);
      acc[1][nt] = __builtin_amdgcn_mfma_scale_f32_32x32x64_f8f6f4(
          A1, Bf, acc[1][nt], 0, 0, 0, SCALE1, 0, SCALE1);
    }
    __syncthreads();   // drains prefetch (issued ~8 MFMAs ago), frees cur
  }

  // ---- threshold + OR. Lane covers channels c = nt*32 + m31.
  unsigned sp = 0;
#pragma unroll
  for (int nt = 0; nt < 4; ++nt) {
    float m0 = -1e30f, m1 = -1e30f;
#pragma unroll
    for (int e = 0; e < 16; ++e) {
      m0 = fmaxf(m0, acc[0][nt][e]);
      m1 = fmaxf(m1, acc[1][nt][e]);
    }
    if (fmaxf(m0, m1) >= THRESH) sp |= (1u << nt);
  }
  sp |= __shfl_xor(sp, 32, 64);   // merge the two row-halves
  if (l < 32 && sp) atomicOr(&poolbits[m31], sp);
  __syncthreads();

  if (tid < 128) {
    unsigned bits = poolbits[tid & 31];
    if ((bits >> (tid >> 5)) & 1)
      pool[(s * 128 + tid) * 15 + fp] = 1;   // benign same-value race across blocks
  }
}

// ---------------- winner (reference get_k_winners semantics), pool in LDS
__global__ __launch_bounds__(256) void winner_kernel(const int* __restrict__ pool,
                                                     float* __restrict__ out) {
  __shared__ int lp[15360];
  __shared__ int sh_v;
  __shared__ int sh_best;
  int tid = threadIdx.x;
  if (tid == 0) { sh_v = 0; sh_best = 0; }
  for (int i = tid; i < 15360; i += 256) lp[i] = pool[i];
  __syncthreads();

  int localv = 0;
  for (int p = tid; p < 1920; p += 256) {
    int c = p / 15, f = p % 15;
    int cnt = 0;
    for (int s = 0; s < 8; ++s) cnt += lp[(s * 128 + c) * 15 + f];
    if (cnt > 0) {
      int early = 8 - cnt; if (early > 7) early = 7;
      localv |= lp[(early * 128 + c) * 15 + f];
    }
  }
  if (localv) atomicOr(&sh_v, 1);
  __syncthreads();

  const int v = sh_v * 8;   // trunc.max() * T
  int localbest = 0;
  for (int p = tid; p < 1920; p += 256) {
    int c = p / 15, f = p % 15;
    int cnt = 0;
    for (int s = 0; s < 8; ++s) cnt += lp[(s * 128 + c) * 15 + f];
    int early = 8 - cnt; if (early > 7) early = 7;
    int val = lp[(early * 128 + c) * 15 + f];
    int total = cnt * (val + v);
    int pack = (total << 12) | (4095 - p);   // max total, then smallest flat idx
    if (pack > localbest) localbest = pack;
  }
  atomicMax(&sh_best, localbest);
  __syncthreads();

  if (tid == 0) {
    int total = sh_best >> 12;
    int p = 4095 - (sh_best & 4095);
    int feat = p / 15;
    out[0] = (total != 0) ? (float)feat : -1.0f;
  }
}

// ---------------------------------------------------------------------------
extern "C" void kernel_launch(void* const* d_in, const int* in_sizes, int n_in,
                              void* d_out, int out_size, void* d_ws, size_t ws_size,
                              hipStream_t stream) {
  (void)in_sizes; (void)n_in; (void)out_size; (void)ws_size;
  const float* X = (const float*)d_in[0];
  const float* W = (const float*)d_in[1];
  unsigned char* Wp8 = (unsigned char*)d_ws;               // 524,288 B
  int* pool = (int*)((char*)d_ws + (1 << 19));             // 61,440 B

  prep_kernel<<<64, 256, 0, stream>>>(W, Wp8, pool);
  conv_pool_kernel<<<3120, 256, 0, stream>>>(X, Wp8, pool);
  winner_kernel<<<1, 256, 0, stream>>>(pool, (float*)d_out);
}

// Round 8
// 110.529 us; speedup vs baseline: 3.4723x; 1.0164x over previous
//
#include <hip/hip_runtime.h>

// ---------------------------------------------------------------------------
// Convnet: 8 overlapping sections, conv [32x16] x 128 ch, threshold 15, pool
// (400,16), winner-take-all -> single channel index.
//
// R7: conflict-free LDS layouts for the fp8 kernel.
//     B: [ko][half][ch][16B] half-planes -> lane stride 16 B (stride-1 b128).
//     A: unpadded 16-B rows (fp8 row = 16 B) -> stride-16 reads, Ash 8 KB,
//        residency up to ~5 blocks/CU. Same R6 MFMA structure otherwise.
// ---------------------------------------------------------------------------

using int4v  = __attribute__((ext_vector_type(4))) int;
using int8v  = __attribute__((ext_vector_type(8))) int;
using f32x16 = __attribute__((ext_vector_type(16))) float;

#define THRESH 15.0f
#define SCALE1 0x7F7F7F7F   // E8M0 127 = 2^0 in every byte

// ---------------- prep: W fp32 -> fp8 e4m3, B-chunk layout:
//   addr = s*65536 + cc*8192 + ko*4096 + half*2048 + c*16 + byte
//   (cc = k64 chunk, ko = k32 half of chunk, half = 16B half of 32 taps)
__global__ __launch_bounds__(256) void prep_kernel(const float* __restrict__ W,
                                                   unsigned char* __restrict__ Wp8,
                                                   int* __restrict__ pool) {
  int t = blockIdx.x * 256 + threadIdx.x;   // 64 blocks -> 16384 threads
  if (t < 15360) pool[t] = 0;
  int s = t >> 11, r = t & 2047, c = r >> 4, b = r & 15;   // b = k32 block
  const float* src = W + ((s * 128 + c) * 512 + b * 32);
  int4v lo, hi;
#pragma unroll
  for (int i = 0; i < 4; ++i) {
    float4 v = *(const float4*)(src + i * 4);
    int p = 0;
    p = __builtin_amdgcn_cvt_pk_fp8_f32(v.x, v.y, p, false);
    p = __builtin_amdgcn_cvt_pk_fp8_f32(v.z, v.w, p, true);
    lo[i] = p;
    float4 u = *(const float4*)(src + 16 + i * 4);
    int q = 0;
    q = __builtin_amdgcn_cvt_pk_fp8_f32(u.x, u.y, q, false);
    q = __builtin_amdgcn_cvt_pk_fp8_f32(u.z, u.w, q, true);
    hi[i] = q;
  }
  unsigned char* base = Wp8 + s * 65536 + (b >> 1) * 8192 + (b & 1) * 4096 + c * 16;
  *(int4v*)(base)        = lo;   // half 0: taps 0..15 of this k32 block
  *(int4v*)(base + 2048) = hi;   // half 1: taps 16..31
}

// ---------------- conv + threshold + pool-OR
// grid: 8 s * 13 t-tiles(32) * 30 fo-tiles(8) = 3120 blocks, 256 threads
// block: M = 256 (32 t x 8 fo), N = 128 ch, K = 512 (k = kt*16+kf)
// wave w: fo offsets {2w, 2w+1}; mfma_scale_f32_32x32x64_f8f6f4:
//   lane holds A[m=lane&31][k=(lane>>5)*32+j] (32 B), B[k][n=lane&31] (32 B),
//   D col = lane&31. Slot j packed identically on A and B -> permutation cancels.
__global__ __launch_bounds__(256, 2) void conv_pool_kernel(const float* __restrict__ X,
                                                           const unsigned char* __restrict__ Wp8,
                                                           int* __restrict__ pool) {
  // 8 fo-shifted copies of the 63-row X patch, fp8: 16 B rows, unpadded
  __shared__ __align__(16) unsigned char Ash[8 * 1008];   // 8064 B
  __shared__ __align__(16) unsigned char Bsh[2 * 8192];   // 16384 B (dbuf)
  __shared__ unsigned poolbits[32];

  const int tid = threadIdx.x;
  const int bid = blockIdx.x;
  const int s   = bid / 390;
  const int rem = bid % 390;
  const int tt  = rem / 30;
  const int ft  = rem % 30;
  const int t0  = (tt == 12) ? 368 : tt * 32;   // overlap recompute; OR idempotent
  const int fo0 = ft * 8, fp = ft >> 1;
  const int srow = s * 400 + t0;                // max 3168; +62 = 3230 in-bounds

  if (tid < 32) poolbits[tid] = 0;

  // ---- stage A: 8 d x 63 rows x 16 fp8 (stride-16 writes, conflict-free)
  for (int i = tid; i < 504; i += 256) {
    int d = i / 63, r = i % 63;
    const float* xs = X + (srow + r) * 256 + fo0 + d;
    int4v pk;
#pragma unroll
    for (int h = 0; h < 4; ++h) {
      int q = 0;
      q = __builtin_amdgcn_cvt_pk_fp8_f32(xs[h * 4 + 0], xs[h * 4 + 1], q, false);
      q = __builtin_amdgcn_cvt_pk_fp8_f32(xs[h * 4 + 2], xs[h * 4 + 3], q, true);
      pk[h] = q;
    }
    *(int4v*)&Ash[d * 1008 + r * 16] = pk;
  }

  f32x16 acc[2][4];
#pragma unroll
  for (int a = 0; a < 2; ++a)
#pragma unroll
    for (int b = 0; b < 4; ++b)
#pragma unroll
      for (int e = 0; e < 16; ++e) acc[a][b][e] = 0.f;

  const int w = tid >> 6, l = tid & 63;
  const int m31 = l & 31, ko = l >> 5;

  const unsigned char* wbase = Wp8 + s * 65536;

  // per-lane LDS base offsets (bytes)
  const int aoff0 = (2 * w) * 1008 + m31 * 16 + ko * 32;       // + ch*64 (+16 hi)
  const int aoff1 = (2 * w + 1) * 1008 + m31 * 16 + ko * 32;
  const int boff  = ko * 4096 + m31 * 16;                      // + nt*512 (+2048 hi)

  // issue B chunk 0 into buf 0 (drained by the next barrier)
#pragma unroll
  for (int it = 0; it < 2; ++it) {
    int off = (it * 256 + tid) * 16;
    __builtin_amdgcn_global_load_lds(
        (const __attribute__((address_space(1))) void*)(wbase + off),
        (__attribute__((address_space(3))) void*)(&Bsh[off]), 16, 0, 0);
  }
  __syncthreads();   // A copies + chunk 0 + poolbits ready

  for (int ch = 0; ch < 8; ++ch) {              // K chunks of 64 (4 kt each)
    const unsigned char* cur = Bsh + (ch & 1) * 8192;
    if (ch < 7) {                               // prefetch next chunk
      const unsigned char* gsrc = wbase + (ch + 1) * 8192;
      unsigned char* dst = Bsh + ((ch + 1) & 1) * 8192;
#pragma unroll
      for (int it = 0; it < 2; ++it) {
        int off = (it * 256 + tid) * 16;
        __builtin_amdgcn_global_load_lds(
            (const __attribute__((address_space(1))) void*)(gsrc + off),
            (__attribute__((address_space(3))) void*)(dst + off), 16, 0, 0);
      }
    }

    // A frags: rows kt = ch*4 + ko*2 + {0,1} (+m31 conv shift), 2x16 B contiguous
    int4v a0lo = *(const int4v*)&Ash[aoff0 + ch * 64];
    int4v a0hi = *(const int4v*)&Ash[aoff0 + ch * 64 + 16];
    int4v a1lo = *(const int4v*)&Ash[aoff1 + ch * 64];
    int4v a1hi = *(const int4v*)&Ash[aoff1 + ch * 64 + 16];
    int8v A0 = {a0lo[0], a0lo[1], a0lo[2], a0lo[3], a0hi[0], a0hi[1], a0hi[2], a0hi[3]};
    int8v A1 = {a1lo[0], a1lo[1], a1lo[2], a1lo[3], a1hi[0], a1hi[1], a1hi[2], a1hi[3]};

    const unsigned char* bb = cur + boff;
#pragma unroll
    for (int nt = 0; nt < 4; ++nt) {
      int4v blo = *(const int4v*)(bb + nt * 512);          // half-plane 0
      int4v bhi = *(const int4v*)(bb + nt * 512 + 2048);   // half-plane 1
      int8v Bf = {blo[0], blo[1], blo[2], blo[3], bhi[0], bhi[1], bhi[2], bhi[3]};
      acc[0][nt] = __builtin_amdgcn_mfma_scale_f32_32x32x64_f8f6f4(
          A0, Bf, acc[0][nt], 0, 0, 0, SCALE1, 0, SCALE1);
      acc[1][nt] = __builtin_amdgcn_mfma_scale_f32_32x32x64_f8f6f4(
          A1, Bf, acc[1][nt], 0, 0, 0, SCALE1, 0, SCALE1);
    }
    __syncthreads();   // drains prefetch, frees cur
  }

  // ---- threshold + OR. Lane covers channels c = nt*32 + m31.
  unsigned sp = 0;
#pragma unroll
  for (int nt = 0; nt < 4; ++nt) {
    float m0 = -1e30f, m1 = -1e30f;
#pragma unroll
    for (int e = 0; e < 16; ++e) {
      m0 = fmaxf(m0, acc[0][nt][e]);
      m1 = fmaxf(m1, acc[1][nt][e]);
    }
    if (fmaxf(m0, m1) >= THRESH) sp |= (1u << nt);
  }
  sp |= __shfl_xor(sp, 32, 64);   // merge the two row-halves
  if (l < 32 && sp) atomicOr(&poolbits[m31], sp);
  __syncthreads();

  if (tid < 128) {
    unsigned bits = poolbits[tid & 31];
    if ((bits >> (tid >> 5)) & 1)
      pool[(s * 128 + tid) * 15 + fp] = 1;   // benign same-value race across blocks
  }
}

// ---------------- winner (reference get_k_winners semantics), pool in LDS
__global__ __launch_bounds__(256) void winner_kernel(const int* __restrict__ pool,
                                                     float* __restrict__ out) {
  __shared__ int lp[15360];
  __shared__ int sh_v;
  __shared__ int sh_best;
  int tid = threadIdx.x;
  if (tid == 0) { sh_v = 0; sh_best = 0; }
  for (int i = tid; i < 15360; i += 256) lp[i] = pool[i];
  __syncthreads();

  int localv = 0;
  for (int p = tid; p < 1920; p += 256) {
    int c = p / 15, f = p % 15;
    int cnt = 0;
    for (int s = 0; s < 8; ++s) cnt += lp[(s * 128 + c) * 15 + f];
    if (cnt > 0) {
      int early = 8 - cnt; if (early > 7) early = 7;
      localv |= lp[(early * 128 + c) * 15 + f];
    }
  }
  if (localv) atomicOr(&sh_v, 1);
  __syncthreads();

  const int v = sh_v * 8;   // trunc.max() * T
  int localbest = 0;
  for (int p = tid; p < 1920; p += 256) {
    int c = p / 15, f = p % 15;
    int cnt = 0;
    for (int s = 0; s < 8; ++s) cnt += lp[(s * 128 + c) * 15 + f];
    int early = 8 - cnt; if (early > 7) early = 7;
    int val = lp[(early * 128 + c) * 15 + f];
    int total = cnt * (val + v);
    int pack = (total << 12) | (4095 - p);   // max total, then smallest flat idx
    if (pack > localbest) localbest = pack;
  }
  atomicMax(&sh_best, localbest);
  __syncthreads();

  if (tid == 0) {
    int total = sh_best >> 12;
    int p = 4095 - (sh_best & 4095);
    int feat = p / 15;
    out[0] = (total != 0) ? (float)feat : -1.0f;
  }
}

// ---------------------------------------------------------------------------
extern "C" void kernel_launch(void* const* d_in, const int* in_sizes, int n_in,
                              void* d_out, int out_size, void* d_ws, size_t ws_size,
                              hipStream_t stream) {
  (void)in_sizes; (void)n_in; (void)out_size; (void)ws_size;
  const float* X = (const float*)d_in[0];
  const float* W = (const float*)d_in[1];
  unsigned char* Wp8 = (unsigned char*)d_ws;               // 524,288 B
  int* pool = (int*)((char*)d_ws + (1 << 19));             // 61,440 B

  prep_kernel<<<64, 256, 0, stream>>>(W, Wp8, pool);
  conv_pool_kernel<<<3120, 256, 0, stream>>>(X, Wp8, pool);
  winner_kernel<<<1, 256, 0, stream>>>(pool, (float*)d_out);
}

// Round 9
// 99.803 us; speedup vs baseline: 3.8455x; 1.1075x over previous
//
#include <hip/hip_runtime.h>

// ---------------------------------------------------------------------------
// Convnet: 8 overlapping sections, conv [32x16] x 128 ch, threshold 15, pool
// (400,16), winner-take-all -> single channel index.
//
// R9: barrier-free K loop. W per section = 64 KB fp8 -> load ALL of it into
//     LDS once (global_load_lds x16/thread), ONE barrier, then 8 K-chunks of
//     pure ds_read+MFMA with no syncs/vmcnt drains (R8 showed the per-chunk
//     barrier lockstep — not bank conflicts — was the limiter; both pipes
//     only ~40% busy). Occupancy stays 2 blocks/CU (AGPR-capped anyway).
// ---------------------------------------------------------------------------

using int4v  = __attribute__((ext_vector_type(4))) int;
using int8v  = __attribute__((ext_vector_type(8))) int;
using f32x16 = __attribute__((ext_vector_type(16))) float;

#define THRESH 15.0f
#define SCALE1 0x7F7F7F7F   // E8M0 127 = 2^0 in every byte

// ---------------- prep: W fp32 -> fp8 e4m3, B layout (per section, 64 KB):
//   addr = s*65536 + cc*8192 + ko*4096 + half*2048 + c*16 + byte
//   (cc = k64 chunk, ko = k32 half of chunk, half = 16B half of 32 taps)
__global__ __launch_bounds__(256) void prep_kernel(const float* __restrict__ W,
                                                   unsigned char* __restrict__ Wp8,
                                                   int* __restrict__ pool) {
  int t = blockIdx.x * 256 + threadIdx.x;   // 64 blocks -> 16384 threads
  if (t < 15360) pool[t] = 0;
  int s = t >> 11, r = t & 2047, c = r >> 4, b = r & 15;   // b = k32 block
  const float* src = W + ((s * 128 + c) * 512 + b * 32);
  int4v lo, hi;
#pragma unroll
  for (int i = 0; i < 4; ++i) {
    float4 v = *(const float4*)(src + i * 4);
    int p = 0;
    p = __builtin_amdgcn_cvt_pk_fp8_f32(v.x, v.y, p, false);
    p = __builtin_amdgcn_cvt_pk_fp8_f32(v.z, v.w, p, true);
    lo[i] = p;
    float4 u = *(const float4*)(src + 16 + i * 4);
    int q = 0;
    q = __builtin_amdgcn_cvt_pk_fp8_f32(u.x, u.y, q, false);
    q = __builtin_amdgcn_cvt_pk_fp8_f32(u.z, u.w, q, true);
    hi[i] = q;
  }
  unsigned char* base = Wp8 + s * 65536 + (b >> 1) * 8192 + (b & 1) * 4096 + c * 16;
  *(int4v*)(base)        = lo;   // half 0: taps 0..15 of this k32 block
  *(int4v*)(base + 2048) = hi;   // half 1: taps 16..31
}

// ---------------- conv + threshold + pool-OR
// grid: 8 s * 13 t-tiles(32) * 30 fo-tiles(8) = 3120 blocks, 256 threads
// block: M = 256 (32 t x 8 fo), N = 128 ch, K = 512 (k = kt*16+kf)
// wave w: fo offsets {2w, 2w+1}; mfma_scale_f32_32x32x64_f8f6f4:
//   lane holds A[m=lane&31][k=(lane>>5)*32+j] (32 B), B[k][n=lane&31] (32 B),
//   D col = lane&31. Slot j packed identically on A and B -> permutation cancels.
__global__ __launch_bounds__(256, 2) void conv_pool_kernel(const float* __restrict__ X,
                                                           const unsigned char* __restrict__ Wp8,
                                                           int* __restrict__ pool) {
  __shared__ __align__(16) unsigned char Ash[8 * 1008];   // 8064 B, 8 fo-shifted copies
  __shared__ __align__(16) unsigned char Bsh[65536];      // whole section's W, fp8
  __shared__ unsigned poolbits[32];

  const int tid = threadIdx.x;
  const int bid = blockIdx.x;
  const int s   = bid / 390;
  const int rem = bid % 390;
  const int tt  = rem / 30;
  const int ft  = rem % 30;
  const int t0  = (tt == 12) ? 368 : tt * 32;   // overlap recompute; OR idempotent
  const int fo0 = ft * 8, fp = ft >> 1;
  const int srow = s * 400 + t0;                // max 3168; +62 = 3230 in-bounds

  if (tid < 32) poolbits[tid] = 0;

  // ---- issue whole-W DMA: 4096 x 16 B, 16 per thread (drained by the barrier)
  {
    const unsigned char* wbase = Wp8 + s * 65536;
#pragma unroll
    for (int it = 0; it < 16; ++it) {
      int off = (it * 256 + tid) * 16;
      __builtin_amdgcn_global_load_lds(
          (const __attribute__((address_space(1))) void*)(wbase + off),
          (__attribute__((address_space(3))) void*)(&Bsh[off]), 16, 0, 0);
    }
  }

  // ---- stage A: 8 d x 63 rows x 16 fp8 (stride-16 writes, conflict-free)
  for (int i = tid; i < 504; i += 256) {
    int d = i / 63, r = i % 63;
    const float* xs = X + (srow + r) * 256 + fo0 + d;
    int4v pk;
#pragma unroll
    for (int h = 0; h < 4; ++h) {
      int q = 0;
      q = __builtin_amdgcn_cvt_pk_fp8_f32(xs[h * 4 + 0], xs[h * 4 + 1], q, false);
      q = __builtin_amdgcn_cvt_pk_fp8_f32(xs[h * 4 + 2], xs[h * 4 + 3], q, true);
      pk[h] = q;
    }
    *(int4v*)&Ash[d * 1008 + r * 16] = pk;
  }

  f32x16 acc[2][4];
#pragma unroll
  for (int a = 0; a < 2; ++a)
#pragma unroll
    for (int b = 0; b < 4; ++b)
#pragma unroll
      for (int e = 0; e < 16; ++e) acc[a][b][e] = 0.f;

  const int w = tid >> 6, l = tid & 63;
  const int m31 = l & 31, ko = l >> 5;

  // per-lane LDS base offsets (bytes)
  const int aoff0 = (2 * w) * 1008 + m31 * 16 + ko * 32;       // + ch*64 (+16 hi)
  const int aoff1 = (2 * w + 1) * 1008 + m31 * 16 + ko * 32;
  const int boff  = ko * 4096 + m31 * 16;                      // + ch*8192 + nt*512 (+2048 hi)

  __syncthreads();   // W DMA + A copies + poolbits all ready; only barrier

  // ---- barrier-free K loop: 8 chunks of 64 taps, pure ds_read + MFMA
#pragma unroll 2
  for (int ch = 0; ch < 8; ++ch) {
    // A frags: rows kt = ch*4 + ko*2 + {0,1} (+m31 conv shift), 2x16 B contiguous
    int4v a0lo = *(const int4v*)&Ash[aoff0 + ch * 64];
    int4v a0hi = *(const int4v*)&Ash[aoff0 + ch * 64 + 16];
    int4v a1lo = *(const int4v*)&Ash[aoff1 + ch * 64];
    int4v a1hi = *(const int4v*)&Ash[aoff1 + ch * 64 + 16];
    int8v A0 = {a0lo[0], a0lo[1], a0lo[2], a0lo[3], a0hi[0], a0hi[1], a0hi[2], a0hi[3]};
    int8v A1 = {a1lo[0], a1lo[1], a1lo[2], a1lo[3], a1hi[0], a1hi[1], a1hi[2], a1hi[3]};

    const unsigned char* bb = Bsh + ch * 8192 + boff;
#pragma unroll
    for (int nt = 0; nt < 4; ++nt) {
      int4v blo = *(const int4v*)(bb + nt * 512);          // half-plane 0
      int4v bhi = *(const int4v*)(bb + nt * 512 + 2048);   // half-plane 1
      int8v Bf = {blo[0], blo[1], blo[2], blo[3], bhi[0], bhi[1], bhi[2], bhi[3]};
      acc[0][nt] = __builtin_amdgcn_mfma_scale_f32_32x32x64_f8f6f4(
          A0, Bf, acc[0][nt], 0, 0, 0, SCALE1, 0, SCALE1);
      acc[1][nt] = __builtin_amdgcn_mfma_scale_f32_32x32x64_f8f6f4(
          A1, Bf, acc[1][nt], 0, 0, 0, SCALE1, 0, SCALE1);
    }
  }

  // ---- threshold + OR. Lane covers channels c = nt*32 + m31.
  unsigned sp = 0;
#pragma unroll
  for (int nt = 0; nt < 4; ++nt) {
    float m0 = -1e30f, m1 = -1e30f;
#pragma unroll
    for (int e = 0; e < 16; ++e) {
      m0 = fmaxf(m0, acc[0][nt][e]);
      m1 = fmaxf(m1, acc[1][nt][e]);
    }
    if (fmaxf(m0, m1) >= THRESH) sp |= (1u << nt);
  }
  sp |= __shfl_xor(sp, 32, 64);   // merge the two row-halves
  __syncthreads();                // all reads of poolbits-era done; reuse safe
  if (l < 32 && sp) atomicOr(&poolbits[m31], sp);
  __syncthreads();

  if (tid < 128) {
    unsigned bits = poolbits[tid & 31];
    if ((bits >> (tid >> 5)) & 1)
      pool[(s * 128 + tid) * 15 + fp] = 1;   // benign same-value race across blocks
  }
}

// ---------------- winner (reference get_k_winners semantics), pool in LDS
__global__ __launch_bounds__(256) void winner_kernel(const int* __restrict__ pool,
                                                     float* __restrict__ out) {
  __shared__ int lp[15360];
  __shared__ int sh_v;
  __shared__ int sh_best;
  int tid = threadIdx.x;
  if (tid == 0) { sh_v = 0; sh_best = 0; }
  for (int i = tid; i < 15360; i += 256) lp[i] = pool[i];
  __syncthreads();

  int localv = 0;
  for (int p = tid; p < 1920; p += 256) {
    int c = p / 15, f = p % 15;
    int cnt = 0;
    for (int s = 0; s < 8; ++s) cnt += lp[(s * 128 + c) * 15 + f];
    if (cnt > 0) {
      int early = 8 - cnt; if (early > 7) early = 7;
      localv |= lp[(early * 128 + c) * 15 + f];
    }
  }
  if (localv) atomicOr(&sh_v, 1);
  __syncthreads();

  const int v = sh_v * 8;   // trunc.max() * T
  int localbest = 0;
  for (int p = tid; p < 1920; p += 256) {
    int c = p / 15, f = p % 15;
    int cnt = 0;
    for (int s = 0; s < 8; ++s) cnt += lp[(s * 128 + c) * 15 + f];
    int early = 8 - cnt; if (early > 7) early = 7;
    int val = lp[(early * 128 + c) * 15 + f];
    int total = cnt * (val + v);
    int pack = (total << 12) | (4095 - p);   // max total, then smallest flat idx
    if (pack > localbest) localbest = pack;
  }
  atomicMax(&sh_best, localbest);
  __syncthreads();

  if (tid == 0) {
    int total = sh_best >> 12;
    int p = 4095 - (sh_best & 4095);
    int feat = p / 15;
    out[0] = (total != 0) ? (float)feat : -1.0f;
  }
}

// ---------------------------------------------------------------------------
extern "C" void kernel_launch(void* const* d_in, const int* in_sizes, int n_in,
                              void* d_out, int out_size, void* d_ws, size_t ws_size,
                              hipStream_t stream) {
  (void)in_sizes; (void)n_in; (void)out_size; (void)ws_size;
  const float* X = (const float*)d_in[0];
  const float* W = (const float*)d_in[1];
  unsigned char* Wp8 = (unsigned char*)d_ws;               // 524,288 B
  int* pool = (int*)((char*)d_ws + (1 << 19));             // 61,440 B

  prep_kernel<<<64, 256, 0, stream>>>(W, Wp8, pool);
  conv_pool_kernel<<<3120, 256, 0, stream>>>(X, Wp8, pool);
  winner_kernel<<<1, 256, 0, stream>>>(pool, (float*)d_out);
}